// Round 12
// baseline (389.561 us; speedup 1.0000x reference)
//
#include <hip/hip_runtime.h>
#include <hip/hip_bf16.h>
#include <hip/hip_fp16.h>
#include <math.h>

#define NNODES 50000
#define NEDGES 1600000
#define ETOT   (NEDGES + NNODES)
#define F_INN  256
#define NEG_SLOPE 0.2f
#define NBUCK  782            // ceil(50000/64) buckets of 64 dst-nodes
#define BCAP   2624           // mean 2112 edges/bucket, +11 sigma margin
#define CNBLK  256            // convert blocks
#define CBT    1024           // convert block threads

// ---------------------------------------------------------------- detect dtype
__global__ __launch_bounds__(128) void detect_kernel(const unsigned int* __restrict__ ei,
                                                     int* __restrict__ flag) {
    __shared__ int nz;
    if (threadIdx.x == 0) nz = 0;
    __syncthreads();
    unsigned int v = ei[2 * threadIdx.x + 1];
    if (v != 0u) nz = 1;
    __syncthreads();
    if (threadIdx.x == 0) *flag = nz;
}

__device__ __forceinline__ void load_edge(const void* ei, bool is32, int i, int& s, int& d) {
    if (i < NEDGES) {
        if (is32) {
            const int* p = (const int*)ei;
            s = p[i]; d = p[NEDGES + i];
        } else {
            const long long* p = (const long long*)ei;
            s = (int)p[i]; d = (int)p[NEDGES + i];
        }
    } else {
        s = i - NEDGES; d = s;           // self loop
    }
}

// ---------------- convert: block-histogram counting sort into bucket slabs
__global__ __launch_bounds__(CBT) void convert_kernel(const void* __restrict__ ei,
                                                      const int* __restrict__ flag,
                                                      int* __restrict__ bcnt,
                                                      int2* __restrict__ bpair) {
    __shared__ int hist[NBUCK];
    __shared__ int base[NBUCK];
    const int t = threadIdx.x;
    const int chunk = (ETOT + CNBLK - 1) / CNBLK;
    const int i0 = blockIdx.x * chunk;
    const int i1 = min(i0 + chunk, ETOT);
    for (int k = t; k < NBUCK; k += CBT) hist[k] = 0;
    __syncthreads();
    const bool is32 = (*flag) != 0;
    for (int i = i0 + t; i < i1; i += CBT) {
        int s, d; load_edge(ei, is32, i, s, d);
        atomicAdd(&hist[d >> 6], 1);
    }
    __syncthreads();
    for (int k = t; k < NBUCK; k += CBT) {
        int c = hist[k];
        base[k] = c ? atomicAdd(&bcnt[k], c) : 0;
        hist[k] = 0;
    }
    __syncthreads();
    for (int i = i0 + t; i < i1; i += CBT) {
        int s, d; load_edge(ei, is32, i, s, d);
        int b = d >> 6;
        int pos = base[b] + atomicAdd(&hist[b], 1);
        bpair[(size_t)b * BCAP + pos] = make_int2(s, d);
    }
}

// ---------------- exclusive scan of the 782 bucket counts (one pass, 1 block)
__global__ __launch_bounds__(1024) void bucket_scan_kernel(const int* __restrict__ bcnt,
                                                           int* __restrict__ bbase,
                                                           int* __restrict__ rowptr) {
    __shared__ int wsum[16];
    const int t = threadIdx.x, lane = t & 63, wid = t >> 6;
    int v = (t < NBUCK) ? bcnt[t] : 0;
    int incl = v;
    #pragma unroll
    for (int off = 1; off < 64; off <<= 1) {
        int u = __shfl_up(incl, off);
        if (lane >= off) incl += u;
    }
    if (lane == 63) wsum[wid] = incl;
    __syncthreads();
    if (wid == 0) {
        int wv = (lane < 16) ? wsum[lane] : 0;
        #pragma unroll
        for (int off = 1; off < 16; off <<= 1) {
            int u = __shfl_up(wv, off);
            if (lane >= off) wv += u;
        }
        if (lane < 16) wsum[lane] = wv;
    }
    __syncthreads();
    int base = (wid == 0) ? 0 : wsum[wid - 1];
    if (t < NBUCK) bbase[t] = base + incl - v;     // exclusive bucket base
    if (t == 0) rowptr[NNODES] = ETOT;             // total is static
}

// ---------- fused: per-bucket count + 64-wide scan -> rowptr + scatter
__global__ __launch_bounds__(256) void bscatter_kernel(const int2* __restrict__ bpair,
                                                       const int* __restrict__ bcnt,
                                                       const int* __restrict__ bbase,
                                                       int* __restrict__ rowptr,
                                                       int* __restrict__ ssrc) {
    __shared__ int cnt[64];
    __shared__ int s_widx[64];
    const int b = blockIdx.x;
    const int t = threadIdx.x;
    if (t < 64) cnt[t] = 0;
    __syncthreads();
    const int n = bcnt[b];
    const int2* bp = bpair + (size_t)b * BCAP;
    for (int i = t; i < n; i += 256) atomicAdd(&cnt[bp[i].y & 63], 1);
    __syncthreads();
    if (t < 64) {                                   // wave 0: 64-wide excl scan
        int v = cnt[t];
        int incl = v;
        #pragma unroll
        for (int off = 1; off < 64; off <<= 1) {
            int u = __shfl_up(incl, off);
            if (t >= off) incl += u;
        }
        int excl = bbase[b] + incl - v;
        int node = (b << 6) + t;
        if (node < NNODES) rowptr[node] = excl;
        s_widx[t] = excl;
    }
    __syncthreads();
    for (int i = t; i < n; i += 256) {
        int2 e = bp[i];
        int pos = atomicAdd(&s_widx[e.y & 63], 1);
        ssrc[pos] = e.x;                            // bucket-local ~8KB window
    }
}

// ------------------------------------------------ GEMM1: h1(half) = x@W1, logits
// double-buffered LDS; xs XOR-swizzled (2-way banks = free), ws padded 132.
__global__ __launch_bounds__(256) void gemm1_kernel(const float* __restrict__ x,
                                                    const float* __restrict__ W,
                                                    const float* __restrict__ atts,
                                                    const float* __restrict__ attd,
                                                    __half2* __restrict__ h1h,
                                                    float* __restrict__ als,
                                                    float* __restrict__ ald) {
    __shared__ float xs[2][32][68];     // element (k,m) at col m ^ ((k&8)<<1)
    __shared__ float ws[2][32][132];
    const int tid = threadIdx.x;
    const int tx = tid & 15, ty = tid >> 4;
    const int row0 = blockIdx.x * 64;
    float acc[4][8];
    #pragma unroll
    for (int r = 0; r < 4; ++r)
        #pragma unroll
        for (int c = 0; c < 8; ++c) acc[r][c] = 0.f;

    const int lr = tid >> 2;            // m index 0..63
    const int lk = (tid & 3) * 8;       // k base {0,8,16,24}
    const int sw = (lk & 8) << 1;       // xs column swizzle for this thread
    const int cl = lr ^ sw;
    const int wk = tid >> 3;            // W row 0..31
    const int wc = (tid & 7) * 16;      // W col base

    const int gr = row0 + lr;
    const bool gok = gr < NNODES;
    const float* xpb = x + (size_t)gr * F_INN + lk;
    const float* wpb = W + (size_t)wk * 128 + wc;

    float4 rx0 = make_float4(0,0,0,0), rx1 = rx0;
    float4 rw0, rw1, rw2, rw3;
    // prologue: tile 0
    if (gok) { rx0 = *(const float4*)xpb; rx1 = *(const float4*)(xpb + 4); }
    rw0 = *(const float4*)(wpb);      rw1 = *(const float4*)(wpb + 4);
    rw2 = *(const float4*)(wpb + 8);  rw3 = *(const float4*)(wpb + 12);
    xs[0][lk+0][cl]=rx0.x; xs[0][lk+1][cl]=rx0.y; xs[0][lk+2][cl]=rx0.z; xs[0][lk+3][cl]=rx0.w;
    xs[0][lk+4][cl]=rx1.x; xs[0][lk+5][cl]=rx1.y; xs[0][lk+6][cl]=rx1.z; xs[0][lk+7][cl]=rx1.w;
    *(float4*)&ws[0][wk][wc]      = rw0;
    *(float4*)&ws[0][wk][wc + 4]  = rw1;
    *(float4*)&ws[0][wk][wc + 8]  = rw2;
    *(float4*)&ws[0][wk][wc + 12] = rw3;
    __syncthreads();

    for (int k0 = 0; k0 < 8; ++k0) {
        const int cur = k0 & 1;
        const bool more = (k0 < 7);
        if (more) {
            const int kk = (k0 + 1) * 32;
            if (gok) {
                const float* xp = xpb + kk;
                rx0 = *(const float4*)xp; rx1 = *(const float4*)(xp + 4);
            }
            const float* wp = wpb + (size_t)kk * 128;
            rw0 = *(const float4*)(wp);      rw1 = *(const float4*)(wp + 4);
            rw2 = *(const float4*)(wp + 8);  rw3 = *(const float4*)(wp + 12);
        }
        #pragma unroll
        for (int k = 0; k < 32; ++k) {
            float4 av = *(const float4*)&xs[cur][k][(ty*4) ^ ((k & 8) << 1)];
            float4 b0 = *(const float4*)&ws[cur][k][tx*8];
            float4 b1 = *(const float4*)&ws[cur][k][tx*8+4];
            const float a_[4] = {av.x,av.y,av.z,av.w};
            const float b_[8] = {b0.x,b0.y,b0.z,b0.w,b1.x,b1.y,b1.z,b1.w};
            #pragma unroll
            for (int r = 0; r < 4; ++r)
                #pragma unroll
                for (int c = 0; c < 8; ++c)
                    acc[r][c] = fmaf(a_[r], b_[c], acc[r][c]);
        }
        if (more) {
            const int nb = cur ^ 1;
            xs[nb][lk+0][cl]=rx0.x; xs[nb][lk+1][cl]=rx0.y; xs[nb][lk+2][cl]=rx0.z; xs[nb][lk+3][cl]=rx0.w;
            xs[nb][lk+4][cl]=rx1.x; xs[nb][lk+5][cl]=rx1.y; xs[nb][lk+6][cl]=rx1.z; xs[nb][lk+7][cl]=rx1.w;
            *(float4*)&ws[nb][wk][wc]      = rw0;
            *(float4*)&ws[nb][wk][wc + 4]  = rw1;
            *(float4*)&ws[nb][wk][wc + 8]  = rw2;
            *(float4*)&ws[nb][wk][wc + 12] = rw3;
        }
        __syncthreads();
    }

    #pragma unroll
    for (int r = 0; r < 4; ++r) {
        int gor = row0 + ty*4 + r;
        bool valid = gor < NNODES;
        float ps = 0.f, pd = 0.f;
        if (valid) {
            float4 pack;
            __half2* pk = (__half2*)&pack;
            pk[0] = __floats2half2_rn(acc[r][0], acc[r][1]);
            pk[1] = __floats2half2_rn(acc[r][2], acc[r][3]);
            pk[2] = __floats2half2_rn(acc[r][4], acc[r][5]);
            pk[3] = __floats2half2_rn(acc[r][6], acc[r][7]);
            *(float4*)(h1h + (size_t)gor*64 + tx*4) = pack;
            #pragma unroll
            for (int c = 0; c < 8; ++c) {
                ps = fmaf(acc[r][c], atts[tx*8 + c], ps);
                pd = fmaf(acc[r][c], attd[tx*8 + c], pd);
            }
        }
        ps += __shfl_xor(ps, 1); ps += __shfl_xor(ps, 2);
        pd += __shfl_xor(pd, 1); pd += __shfl_xor(pd, 2);
        if (valid && (tx & 3) == 0) {
            int hd = tx >> 2;
            als[gor*4 + hd] = ps;
            ald[gor*4 + hd] = pd;
        }
    }
}

// ------------------------------------------------ GEMM2: h2 = x2@W2, logits
__global__ __launch_bounds__(256) void gemm2_kernel(const float* __restrict__ x2,
                                                    const float* __restrict__ W,
                                                    const float* __restrict__ atts,
                                                    const float* __restrict__ attd,
                                                    float* __restrict__ h2,
                                                    float* __restrict__ als,
                                                    float* __restrict__ ald) {
    __shared__ float xs[2][32][68];
    __shared__ float ws[2][32][68];
    const int tid = threadIdx.x;
    const int tx = tid & 15, ty = tid >> 4;
    const int row0 = blockIdx.x * 64;
    float acc[4][4];
    #pragma unroll
    for (int r = 0; r < 4; ++r)
        #pragma unroll
        for (int c = 0; c < 4; ++c) acc[r][c] = 0.f;

    const int lr = tid >> 2;
    const int lk = (tid & 3) * 8;
    const int sw = (lk & 8) << 1;
    const int cl = lr ^ sw;
    const int wk = tid >> 3;
    const int wc = (tid & 7) * 8;

    const int gr = row0 + lr;
    const bool gok = gr < NNODES;
    const float* xpb = x2 + (size_t)gr * 128 + lk;
    const float* wpb = W + (size_t)wk * 64 + wc;

    float4 rx0 = make_float4(0,0,0,0), rx1 = rx0;
    float4 rw0, rw1;
    if (gok) { rx0 = *(const float4*)xpb; rx1 = *(const float4*)(xpb + 4); }
    rw0 = *(const float4*)(wpb); rw1 = *(const float4*)(wpb + 4);
    xs[0][lk+0][cl]=rx0.x; xs[0][lk+1][cl]=rx0.y; xs[0][lk+2][cl]=rx0.z; xs[0][lk+3][cl]=rx0.w;
    xs[0][lk+4][cl]=rx1.x; xs[0][lk+5][cl]=rx1.y; xs[0][lk+6][cl]=rx1.z; xs[0][lk+7][cl]=rx1.w;
    *(float4*)&ws[0][wk][wc]     = rw0;
    *(float4*)&ws[0][wk][wc + 4] = rw1;
    __syncthreads();

    for (int k0 = 0; k0 < 4; ++k0) {
        const int cur = k0 & 1;
        const bool more = (k0 < 3);
        if (more) {
            const int kk = (k0 + 1) * 32;
            if (gok) {
                const float* xp = xpb + kk;
                rx0 = *(const float4*)xp; rx1 = *(const float4*)(xp + 4);
            }
            const float* wp = wpb + (size_t)kk * 64;
            rw0 = *(const float4*)(wp); rw1 = *(const float4*)(wp + 4);
        }
        #pragma unroll
        for (int k = 0; k < 32; ++k) {
            float4 av = *(const float4*)&xs[cur][k][(ty*4) ^ ((k & 8) << 1)];
            float4 bv = *(const float4*)&ws[cur][k][tx*4];
            const float a_[4] = {av.x,av.y,av.z,av.w};
            const float b_[4] = {bv.x,bv.y,bv.z,bv.w};
            #pragma unroll
            for (int r = 0; r < 4; ++r)
                #pragma unroll
                for (int c = 0; c < 4; ++c)
                    acc[r][c] = fmaf(a_[r], b_[c], acc[r][c]);
        }
        if (more) {
            const int nb = cur ^ 1;
            xs[nb][lk+0][cl]=rx0.x; xs[nb][lk+1][cl]=rx0.y; xs[nb][lk+2][cl]=rx0.z; xs[nb][lk+3][cl]=rx0.w;
            xs[nb][lk+4][cl]=rx1.x; xs[nb][lk+5][cl]=rx1.y; xs[nb][lk+6][cl]=rx1.z; xs[nb][lk+7][cl]=rx1.w;
            *(float4*)&ws[nb][wk][wc]     = rw0;
            *(float4*)&ws[nb][wk][wc + 4] = rw1;
        }
        __syncthreads();
    }

    #pragma unroll
    for (int r = 0; r < 4; ++r) {
        int gor = row0 + ty*4 + r;
        bool valid = gor < NNODES;
        float ps = 0.f, pd = 0.f;
        if (valid) {
            *(float4*)&h2[(size_t)gor*64 + tx*4] = make_float4(acc[r][0],acc[r][1],acc[r][2],acc[r][3]);
            #pragma unroll
            for (int c = 0; c < 4; ++c) {
                ps = fmaf(acc[r][c], atts[tx*4 + c], ps);
                pd = fmaf(acc[r][c], attd[tx*4 + c], pd);
            }
        }
        ps += __shfl_xor(ps, 1); ps += __shfl_xor(ps, 2);
        ps += __shfl_xor(ps, 4); ps += __shfl_xor(ps, 8);
        pd += __shfl_xor(pd, 1); pd += __shfl_xor(pd, 2);
        pd += __shfl_xor(pd, 4); pd += __shfl_xor(pd, 8);
        if (valid && tx == 0) {
            als[gor] = ps;
            ald[gor] = pd;
        }
    }
}

__device__ __forceinline__ float lrelu(float e) { return e > 0.f ? e : NEG_SLOPE * e; }

// ----------------------------------- layer-1 edge softmax+aggregate (wave/node)
__global__ __launch_bounds__(256) void edge1_kernel(const int* __restrict__ rowptr,
                                                    const int* __restrict__ ssrc,
                                                    const float* __restrict__ als,
                                                    const float* __restrict__ ald,
                                                    const __half2* __restrict__ h1h,
                                                    const float* __restrict__ b1,
                                                    float* __restrict__ x2) {
    __shared__ float s_alpha[4][256];
    __shared__ int   s_sidx[4][64];
    __shared__ int   s_nch[4];
    const int lane = threadIdx.x & 63;
    const int wid  = threadIdx.x >> 6;
    const int d = blockIdx.x * 4 + wid;
    const int start = rowptr[d], end = rowptr[d + 1];
    const int deg = end - start;
    float4 aldv = *(const float4*)&ald[d * 4];

    float l0=0.f, l1=0.f, l2=0.f, l3=0.f;
    float4 ex0 = make_float4(0,0,0,0), ex1 = ex0;
    int ss0 = 0, ss1 = 0;
    int it = 0;
    for (int j = start + lane; j < end; j += 64, ++it) {
        int s = ssrc[j];
        float4 a = *(const float4*)&als[s * 4];
        float e0 = __expf(lrelu(a.x + aldv.x));
        float e1 = __expf(lrelu(a.y + aldv.y));
        float e2 = __expf(lrelu(a.z + aldv.z));
        float e3 = __expf(lrelu(a.w + aldv.w));
        if (it == 0)      { ex0 = make_float4(e0,e1,e2,e3); ss0 = s; }
        else if (it == 1) { ex1 = make_float4(e0,e1,e2,e3); ss1 = s; }
        l0 += e0; l1 += e1; l2 += e2; l3 += e3;
    }
    #pragma unroll
    for (int off = 32; off >= 1; off >>= 1) {
        l0 += __shfl_xor(l0, off); l1 += __shfl_xor(l1, off);
        l2 += __shfl_xor(l2, off); l3 += __shfl_xor(l3, off);
    }
    float il0 = 1.f/l0, il1 = 1.f/l1, il2 = 1.f/l2, il3 = 1.f/l3;

    const int nch = (deg + 63) >> 6;
    if (lane == 0) s_nch[wid] = nch;
    __syncthreads();
    const int maxch = max(max(s_nch[0], s_nch[1]), max(s_nch[2], s_nch[3]));

    const int h = lane >> 4;
    float s0 = 0.f, s1 = 0.f;
    for (int c = 0; c < maxch; ++c) {
        const int base = start + c * 64;
        if (c < nch) {
            int j = base + lane;
            if (j < end) {
                int s; float4 ex;
                if (c == 0)      { s = ss0; ex = ex0; }
                else if (c == 1) { s = ss1; ex = ex1; }
                else {
                    s = ssrc[j];
                    float4 a = *(const float4*)&als[s * 4];
                    ex = make_float4(__expf(lrelu(a.x + aldv.x)),
                                     __expf(lrelu(a.y + aldv.y)),
                                     __expf(lrelu(a.z + aldv.z)),
                                     __expf(lrelu(a.w + aldv.w)));
                }
                s_sidx[wid][lane] = s;
                float4 al = make_float4(ex.x*il0, ex.y*il1, ex.z*il2, ex.w*il3);
                *(float4*)&s_alpha[wid][lane * 4] = al;
            }
        }
        __syncthreads();
        if (c < nch) {
            const int cnt = min(64, end - base);
            int jj = 0;
            for (; jj + 3 < cnt; jj += 4) {
                int sA = __builtin_amdgcn_readfirstlane(s_sidx[wid][jj]);
                int sB = __builtin_amdgcn_readfirstlane(s_sidx[wid][jj + 1]);
                int sC = __builtin_amdgcn_readfirstlane(s_sidx[wid][jj + 2]);
                int sD = __builtin_amdgcn_readfirstlane(s_sidx[wid][jj + 3]);
                float aA = s_alpha[wid][jj*4 + h];
                float aB = s_alpha[wid][jj*4 + 4 + h];
                float aC = s_alpha[wid][jj*4 + 8 + h];
                float aD = s_alpha[wid][jj*4 + 12 + h];
                float2 hA = __half22float2(h1h[(size_t)sA * 64 + lane]);
                float2 hB = __half22float2(h1h[(size_t)sB * 64 + lane]);
                float2 hC = __half22float2(h1h[(size_t)sC * 64 + lane]);
                float2 hD = __half22float2(h1h[(size_t)sD * 64 + lane]);
                s0 = fmaf(hA.x, aA, s0); s1 = fmaf(hA.y, aA, s1);
                s0 = fmaf(hB.x, aB, s0); s1 = fmaf(hB.y, aB, s1);
                s0 = fmaf(hC.x, aC, s0); s1 = fmaf(hC.y, aC, s1);
                s0 = fmaf(hD.x, aD, s0); s1 = fmaf(hD.y, aD, s1);
            }
            for (; jj < cnt; ++jj) {
                int sA = __builtin_amdgcn_readfirstlane(s_sidx[wid][jj]);
                float aA = s_alpha[wid][jj*4 + h];
                float2 hA = __half22float2(h1h[(size_t)sA * 64 + lane]);
                s0 = fmaf(hA.x, aA, s0); s1 = fmaf(hA.y, aA, s1);
            }
        }
        __syncthreads();
    }
    const int col = lane << 1;
    float o0 = s0 + b1[col], o1 = s1 + b1[col + 1];
    o0 = o0 > 0.f ? o0 : expm1f(o0);         // ELU
    o1 = o1 > 0.f ? o1 : expm1f(o1);
    *(float2*)&x2[(size_t)d * 128 + col] = make_float2(o0, o1);
}

// ----------------------------------- layer-2 edge softmax+aggregate (wave/node)
__global__ __launch_bounds__(256) void edge2_kernel(const int* __restrict__ rowptr,
                                                    const int* __restrict__ ssrc,
                                                    const float* __restrict__ als,
                                                    const float* __restrict__ ald,
                                                    const float* __restrict__ h2,
                                                    const float* __restrict__ b2,
                                                    float* __restrict__ out) {
    __shared__ float s_alpha[4][64];
    __shared__ int   s_sidx[4][64];
    __shared__ int   s_nch[4];
    const int lane = threadIdx.x & 63;
    const int wid  = threadIdx.x >> 6;
    const int d = blockIdx.x * 4 + wid;
    const int start = rowptr[d], end = rowptr[d + 1];
    const int deg = end - start;
    float aldd = ald[d];

    float l = 0.f;
    float ex0 = 0.f, ex1 = 0.f;
    int ss0 = 0, ss1 = 0;
    int it = 0;
    for (int j = start + lane; j < end; j += 64, ++it) {
        int s = ssrc[j];
        float e = __expf(lrelu(als[s] + aldd));
        if (it == 0)      { ex0 = e; ss0 = s; }
        else if (it == 1) { ex1 = e; ss1 = s; }
        l += e;
    }
    #pragma unroll
    for (int off = 32; off >= 1; off >>= 1) l += __shfl_xor(l, off);
    float invl = 1.f / l;

    const int nch = (deg + 63) >> 6;
    if (lane == 0) s_nch[wid] = nch;
    __syncthreads();
    const int maxch = max(max(s_nch[0], s_nch[1]), max(s_nch[2], s_nch[3]));

    float acc = 0.f;
    for (int c = 0; c < maxch; ++c) {
        const int base = start + c * 64;
        if (c < nch) {
            int j = base + lane;
            if (j < end) {
                int s; float e;
                if (c == 0)      { s = ss0; e = ex0; }
                else if (c == 1) { s = ss1; e = ex1; }
                else { s = ssrc[j]; e = __expf(lrelu(als[s] + aldd)); }
                s_sidx[wid][lane] = s;
                s_alpha[wid][lane] = e * invl;
            }
        }
        __syncthreads();
        if (c < nch) {
            const int cnt = min(64, end - base);
            int jj = 0;
            for (; jj + 3 < cnt; jj += 4) {
                int sA = __builtin_amdgcn_readfirstlane(s_sidx[wid][jj]);
                int sB = __builtin_amdgcn_readfirstlane(s_sidx[wid][jj + 1]);
                int sC = __builtin_amdgcn_readfirstlane(s_sidx[wid][jj + 2]);
                int sD = __builtin_amdgcn_readfirstlane(s_sidx[wid][jj + 3]);
                float aA = s_alpha[wid][jj],     aB = s_alpha[wid][jj + 1];
                float aC = s_alpha[wid][jj + 2], aD = s_alpha[wid][jj + 3];
                float hA = h2[(size_t)sA * 64 + lane];
                float hB = h2[(size_t)sB * 64 + lane];
                float hC = h2[(size_t)sC * 64 + lane];
                float hD = h2[(size_t)sD * 64 + lane];
                acc = fmaf(hA, aA, acc);
                acc = fmaf(hB, aB, acc);
                acc = fmaf(hC, aC, acc);
                acc = fmaf(hD, aD, acc);
            }
            for (; jj < cnt; ++jj) {
                int sA = __builtin_amdgcn_readfirstlane(s_sidx[wid][jj]);
                float aA = s_alpha[wid][jj];
                acc = fmaf(h2[(size_t)sA * 64 + lane], aA, acc);
            }
        }
        __syncthreads();
    }
    out[(size_t)d * 64 + lane] = acc + b2[lane];
}

// ---------------------------------------------------------------------- launch
extern "C" void kernel_launch(void* const* d_in, const int* in_sizes, int n_in,
                              void* d_out, int out_size, void* d_ws, size_t ws_size,
                              hipStream_t stream) {
    const float* x   = (const float*)d_in[0];
    const void*  ei  = d_in[1];
    const float* W1  = (const float*)d_in[2];
    const float* as1 = (const float*)d_in[3];
    const float* ad1 = (const float*)d_in[4];
    const float* b1  = (const float*)d_in[5];
    const float* W2  = (const float*)d_in[6];
    const float* as2 = (const float*)d_in[7];
    const float* ad2 = (const float*)d_in[8];
    const float* b2  = (const float*)d_in[9];
    float* out = (float*)d_out;

    char* p = (char*)d_ws;
    auto alloc = [&](size_t bytes) {
        char* r = p;
        p += (bytes + 255) & ~(size_t)255;
        return r;
    };
    int2*     bpair  = (int2*)alloc(sizeof(int2) * (size_t)NBUCK * BCAP);
    int*      bcnt   = (int*)alloc(sizeof(int) * NBUCK);
    int*      bbase  = (int*)alloc(sizeof(int) * NBUCK);
    int*      ssrc   = (int*)alloc(sizeof(int) * ETOT);
    int*      rowptr = (int*)alloc(sizeof(int) * (NNODES + 1));
    int*      flag   = (int*)alloc(256);
    float*    als1   = (float*)alloc(sizeof(float) * NNODES * 4);
    float*    ald1   = (float*)alloc(sizeof(float) * NNODES * 4);
    float*    als2v  = (float*)alloc(sizeof(float) * NNODES);
    float*    ald2v  = (float*)alloc(sizeof(float) * NNODES);
    __half2*  h1h    = (__half2*)alloc(sizeof(__half2) * NNODES * 64);
    float*    x2     = (float*)alloc(sizeof(float) * NNODES * 128);
    float*    h2     = (float*)alloc(sizeof(float) * NNODES * 64);

    hipMemsetAsync(bcnt, 0, sizeof(int) * NBUCK, stream);

    detect_kernel<<<1, 128, 0, stream>>>((const unsigned int*)ei, flag);
    convert_kernel<<<CNBLK, CBT, 0, stream>>>(ei, flag, bcnt, bpair);
    bucket_scan_kernel<<<1, 1024, 0, stream>>>(bcnt, bbase, rowptr);
    bscatter_kernel<<<NBUCK, 256, 0, stream>>>(bpair, bcnt, bbase, rowptr, ssrc);
    gemm1_kernel<<<(NNODES + 63) / 64, 256, 0, stream>>>(x, W1, as1, ad1, h1h, als1, ald1);
    edge1_kernel<<<(NNODES + 3) / 4, 256, 0, stream>>>(rowptr, ssrc, als1, ald1, h1h, b1, x2);
    gemm2_kernel<<<(NNODES + 63) / 64, 256, 0, stream>>>(x2, W2, as2, ad2, h2, als2v, ald2v);
    edge2_kernel<<<(NNODES + 3) / 4, 256, 0, stream>>>(rowptr, ssrc, als2v, ald2v, h2, b2, out);
}

// Round 13
// 342.673 us; speedup vs baseline: 1.1368x; 1.1368x over previous
//
#include <hip/hip_runtime.h>
#include <hip/hip_bf16.h>
#include <hip/hip_fp16.h>
#include <math.h>

#define NNODES 50000
#define NEDGES 1600000
#define ETOT   (NEDGES + NNODES)
#define F_INN  256
#define NEG_SLOPE 0.2f
#define NBUCK  782            // ceil(50000/64) buckets of 64 dst-nodes
#define BCAP   2624           // mean 2112 edges/bucket, +11 sigma margin
#define CNBLK  256            // convert blocks
#define CBT    1024           // convert block threads

// ---------------------------------------------------------------- detect dtype
__global__ __launch_bounds__(128) void detect_kernel(const unsigned int* __restrict__ ei,
                                                     int* __restrict__ flag) {
    __shared__ int nz;
    if (threadIdx.x == 0) nz = 0;
    __syncthreads();
    unsigned int v = ei[2 * threadIdx.x + 1];
    if (v != 0u) nz = 1;
    __syncthreads();
    if (threadIdx.x == 0) *flag = nz;
}

__device__ __forceinline__ void load_edge(const void* ei, bool is32, int i, int& s, int& d) {
    if (i < NEDGES) {
        if (is32) {
            const int* p = (const int*)ei;
            s = p[i]; d = p[NEDGES + i];
        } else {
            const long long* p = (const long long*)ei;
            s = (int)p[i]; d = (int)p[NEDGES + i];
        }
    } else {
        s = i - NEDGES; d = s;           // self loop
    }
}

// ---------------- convert: block-histogram counting sort into bucket slabs
__global__ __launch_bounds__(CBT) void convert_kernel(const void* __restrict__ ei,
                                                      const int* __restrict__ flag,
                                                      int* __restrict__ bcnt,
                                                      int2* __restrict__ bpair) {
    __shared__ int hist[NBUCK];
    __shared__ int base[NBUCK];
    const int t = threadIdx.x;
    const int chunk = (ETOT + CNBLK - 1) / CNBLK;
    const int i0 = blockIdx.x * chunk;
    const int i1 = min(i0 + chunk, ETOT);
    for (int k = t; k < NBUCK; k += CBT) hist[k] = 0;
    __syncthreads();
    const bool is32 = (*flag) != 0;
    for (int i = i0 + t; i < i1; i += CBT) {
        int s, d; load_edge(ei, is32, i, s, d);
        atomicAdd(&hist[d >> 6], 1);
    }
    __syncthreads();
    for (int k = t; k < NBUCK; k += CBT) {
        int c = hist[k];
        base[k] = c ? atomicAdd(&bcnt[k], c) : 0;
        hist[k] = 0;
    }
    __syncthreads();
    for (int i = i0 + t; i < i1; i += CBT) {
        int s, d; load_edge(ei, is32, i, s, d);
        int b = d >> 6;
        int pos = base[b] + atomicAdd(&hist[b], 1);
        bpair[(size_t)b * BCAP + pos] = make_int2(s, d);
    }
}

// ---------------- exclusive scan of the 782 bucket counts (one pass, 1 block)
__global__ __launch_bounds__(1024) void bucket_scan_kernel(const int* __restrict__ bcnt,
                                                           int* __restrict__ bbase,
                                                           int* __restrict__ rowptr) {
    __shared__ int wsum[16];
    const int t = threadIdx.x, lane = t & 63, wid = t >> 6;
    int v = (t < NBUCK) ? bcnt[t] : 0;
    int incl = v;
    #pragma unroll
    for (int off = 1; off < 64; off <<= 1) {
        int u = __shfl_up(incl, off);
        if (lane >= off) incl += u;
    }
    if (lane == 63) wsum[wid] = incl;
    __syncthreads();
    if (wid == 0) {
        int wv = (lane < 16) ? wsum[lane] : 0;
        #pragma unroll
        for (int off = 1; off < 16; off <<= 1) {
            int u = __shfl_up(wv, off);
            if (lane >= off) wv += u;
        }
        if (lane < 16) wsum[lane] = wv;
    }
    __syncthreads();
    int base = (wid == 0) ? 0 : wsum[wid - 1];
    if (t < NBUCK) bbase[t] = base + incl - v;     // exclusive bucket base
    if (t == 0) rowptr[NNODES] = ETOT;             // total is static
}

// ---------- fused: per-bucket count + 64-wide scan -> rowptr + scatter
__global__ __launch_bounds__(256) void bscatter_kernel(const int2* __restrict__ bpair,
                                                       const int* __restrict__ bcnt,
                                                       const int* __restrict__ bbase,
                                                       int* __restrict__ rowptr,
                                                       int* __restrict__ ssrc) {
    __shared__ int cnt[64];
    __shared__ int s_widx[64];
    const int b = blockIdx.x;
    const int t = threadIdx.x;
    if (t < 64) cnt[t] = 0;
    __syncthreads();
    const int n = bcnt[b];
    const int2* bp = bpair + (size_t)b * BCAP;
    for (int i = t; i < n; i += 256) atomicAdd(&cnt[bp[i].y & 63], 1);
    __syncthreads();
    if (t < 64) {                                   // wave 0: 64-wide excl scan
        int v = cnt[t];
        int incl = v;
        #pragma unroll
        for (int off = 1; off < 64; off <<= 1) {
            int u = __shfl_up(incl, off);
            if (t >= off) incl += u;
        }
        int excl = bbase[b] + incl - v;
        int node = (b << 6) + t;
        if (node < NNODES) rowptr[node] = excl;
        s_widx[t] = excl;
    }
    __syncthreads();
    for (int i = t; i < n; i += 256) {
        int2 e = bp[i];
        int pos = atomicAdd(&s_widx[e.y & 63], 1);
        ssrc[pos] = e.x;                            // bucket-local ~8KB window
    }
}

// ------------------------------------------------ GEMM1: h1(half) = x@W1, logits
// single-buffered (VGPR-lean, occupancy over pipelining — r12 lesson);
// xs XOR-swizzle (store 2-way); ws intra-row pad +4/32 cols -> read 2-way (free).
__global__ __launch_bounds__(256) void gemm1_kernel(const float* __restrict__ x,
                                                    const float* __restrict__ W,
                                                    const float* __restrict__ atts,
                                                    const float* __restrict__ attd,
                                                    __half2* __restrict__ h1h,
                                                    float* __restrict__ als,
                                                    float* __restrict__ ald) {
    __shared__ float xs[32][68];     // element (k,m) at col m ^ ((k&8)<<1)
    __shared__ float ws[32][144];    // col c at offset c + 4*(c>>5)
    const int tid = threadIdx.x;
    const int tx = tid & 15, ty = tid >> 4;
    const int row0 = blockIdx.x * 64;
    float acc[4][8];
    #pragma unroll
    for (int r = 0; r < 4; ++r)
        #pragma unroll
        for (int c = 0; c < 8; ++c) acc[r][c] = 0.f;

    const int lr = tid >> 2;            // m 0..63
    const int lk = (tid & 3) * 8;       // k base {0,8,16,24}
    const int cl = lr ^ ((lk & 8) << 1);
    const int wk = tid >> 3;            // W row 0..31
    const int wc = (tid & 7) * 16;      // W col base (16-aligned, one 32-block)
    const int wbase = wc + ((wc >> 5) << 2);
    const int rb0 = tx * 8 + ((tx >> 2) << 2);   // read offset for cols tx*8..

    const int gr = row0 + lr;
    const bool gok = gr < NNODES;
    const float* xpb = x + (size_t)gr * F_INN + lk;
    const float* wpb = W + (size_t)wk * 128 + wc;

    for (int k0 = 0; k0 < F_INN; k0 += 32) {
        float4 v0 = make_float4(0.f,0.f,0.f,0.f), v1 = v0;
        if (gok) {
            const float* xp = xpb + k0;
            v0 = *(const float4*)xp; v1 = *(const float4*)(xp + 4);
        }
        xs[lk+0][cl]=v0.x; xs[lk+1][cl]=v0.y; xs[lk+2][cl]=v0.z; xs[lk+3][cl]=v0.w;
        xs[lk+4][cl]=v1.x; xs[lk+5][cl]=v1.y; xs[lk+6][cl]=v1.z; xs[lk+7][cl]=v1.w;
        const float* wp = wpb + (size_t)k0 * 128;
        #pragma unroll
        for (int q = 0; q < 4; ++q)
            *(float4*)&ws[wk][wbase + q*4] = *(const float4*)(wp + q*4);
        __syncthreads();
        #pragma unroll
        for (int k = 0; k < 32; ++k) {
            float4 av = *(const float4*)&xs[k][(ty*4) ^ ((k & 8) << 1)];
            float4 b0 = *(const float4*)&ws[k][rb0];
            float4 b1 = *(const float4*)&ws[k][rb0 + 4];
            const float a_[4] = {av.x,av.y,av.z,av.w};
            const float b_[8] = {b0.x,b0.y,b0.z,b0.w,b1.x,b1.y,b1.z,b1.w};
            #pragma unroll
            for (int r = 0; r < 4; ++r)
                #pragma unroll
                for (int c = 0; c < 8; ++c)
                    acc[r][c] = fmaf(a_[r], b_[c], acc[r][c]);
        }
        __syncthreads();
    }

    #pragma unroll
    for (int r = 0; r < 4; ++r) {
        int gor = row0 + ty*4 + r;
        bool valid = gor < NNODES;
        float ps = 0.f, pd = 0.f;
        if (valid) {
            float4 pack;
            __half2* pk = (__half2*)&pack;
            pk[0] = __floats2half2_rn(acc[r][0], acc[r][1]);
            pk[1] = __floats2half2_rn(acc[r][2], acc[r][3]);
            pk[2] = __floats2half2_rn(acc[r][4], acc[r][5]);
            pk[3] = __floats2half2_rn(acc[r][6], acc[r][7]);
            *(float4*)(h1h + (size_t)gor*64 + tx*4) = pack;
            #pragma unroll
            for (int c = 0; c < 8; ++c) {
                ps = fmaf(acc[r][c], atts[tx*8 + c], ps);
                pd = fmaf(acc[r][c], attd[tx*8 + c], pd);
            }
        }
        ps += __shfl_xor(ps, 1); ps += __shfl_xor(ps, 2);
        pd += __shfl_xor(pd, 1); pd += __shfl_xor(pd, 2);
        if (valid && (tx & 3) == 0) {
            int hd = tx >> 2;
            als[gor*4 + hd] = ps;
            ald[gor*4 + hd] = pd;
        }
    }
}

// ------------------------------------------------ GEMM2: h2 = x2@W2, logits
__global__ __launch_bounds__(256) void gemm2_kernel(const float* __restrict__ x2,
                                                    const float* __restrict__ W,
                                                    const float* __restrict__ atts,
                                                    const float* __restrict__ attd,
                                                    float* __restrict__ h2,
                                                    float* __restrict__ als,
                                                    float* __restrict__ ald) {
    __shared__ float xs[32][68];
    __shared__ float ws[32][72];     // col c at offset c + 4*(c>>5)
    const int tid = threadIdx.x;
    const int tx = tid & 15, ty = tid >> 4;
    const int row0 = blockIdx.x * 64;
    float acc[4][4];
    #pragma unroll
    for (int r = 0; r < 4; ++r)
        #pragma unroll
        for (int c = 0; c < 4; ++c) acc[r][c] = 0.f;

    const int lr = tid >> 2;
    const int lk = (tid & 3) * 8;
    const int cl = lr ^ ((lk & 8) << 1);
    const int wk = tid >> 3;
    const int wc = (tid & 7) * 8;       // 8-aligned, stays in one 32-block
    const int wbase = wc + ((wc >> 5) << 2);
    const int rb = tx * 4 + ((tx >> 3) << 2);

    const int gr = row0 + lr;
    const bool gok = gr < NNODES;
    const float* xpb = x2 + (size_t)gr * 128 + lk;
    const float* wpb = W + (size_t)wk * 64 + wc;

    for (int k0 = 0; k0 < 128; k0 += 32) {
        float4 v0 = make_float4(0.f,0.f,0.f,0.f), v1 = v0;
        if (gok) {
            const float* xp = xpb + k0;
            v0 = *(const float4*)xp; v1 = *(const float4*)(xp + 4);
        }
        xs[lk+0][cl]=v0.x; xs[lk+1][cl]=v0.y; xs[lk+2][cl]=v0.z; xs[lk+3][cl]=v0.w;
        xs[lk+4][cl]=v1.x; xs[lk+5][cl]=v1.y; xs[lk+6][cl]=v1.z; xs[lk+7][cl]=v1.w;
        const float* wp = wpb + (size_t)k0 * 64;
        *(float4*)&ws[wk][wbase]     = *(const float4*)wp;
        *(float4*)&ws[wk][wbase + 4] = *(const float4*)(wp + 4);
        __syncthreads();
        #pragma unroll
        for (int k = 0; k < 32; ++k) {
            float4 av = *(const float4*)&xs[k][(ty*4) ^ ((k & 8) << 1)];
            float4 bv = *(const float4*)&ws[k][rb];
            const float a_[4] = {av.x,av.y,av.z,av.w};
            const float b_[4] = {bv.x,bv.y,bv.z,bv.w};
            #pragma unroll
            for (int r = 0; r < 4; ++r)
                #pragma unroll
                for (int c = 0; c < 4; ++c)
                    acc[r][c] = fmaf(a_[r], b_[c], acc[r][c]);
        }
        __syncthreads();
    }

    #pragma unroll
    for (int r = 0; r < 4; ++r) {
        int gor = row0 + ty*4 + r;
        bool valid = gor < NNODES;
        float ps = 0.f, pd = 0.f;
        if (valid) {
            *(float4*)&h2[(size_t)gor*64 + tx*4] = make_float4(acc[r][0],acc[r][1],acc[r][2],acc[r][3]);
            #pragma unroll
            for (int c = 0; c < 4; ++c) {
                ps = fmaf(acc[r][c], atts[tx*4 + c], ps);
                pd = fmaf(acc[r][c], attd[tx*4 + c], pd);
            }
        }
        ps += __shfl_xor(ps, 1); ps += __shfl_xor(ps, 2);
        ps += __shfl_xor(ps, 4); ps += __shfl_xor(ps, 8);
        pd += __shfl_xor(pd, 1); pd += __shfl_xor(pd, 2);
        pd += __shfl_xor(pd, 4); pd += __shfl_xor(pd, 8);
        if (valid && tx == 0) {
            als[gor] = ps;
            ald[gor] = pd;
        }
    }
}

__device__ __forceinline__ float lrelu(float e) { return e > 0.f ? e : NEG_SLOPE * e; }

// ----------------------------------- layer-1 edge softmax+aggregate (wave/node)
__global__ __launch_bounds__(256) void edge1_kernel(const int* __restrict__ rowptr,
                                                    const int* __restrict__ ssrc,
                                                    const float* __restrict__ als,
                                                    const float* __restrict__ ald,
                                                    const __half2* __restrict__ h1h,
                                                    const float* __restrict__ b1,
                                                    float* __restrict__ x2) {
    __shared__ float s_alpha[4][256];
    __shared__ int   s_sidx[4][64];
    __shared__ int   s_nch[4];
    const int lane = threadIdx.x & 63;
    const int wid  = threadIdx.x >> 6;
    const int d = blockIdx.x * 4 + wid;
    const int start = rowptr[d], end = rowptr[d + 1];
    const int deg = end - start;
    float4 aldv = *(const float4*)&ald[d * 4];

    float l0=0.f, l1=0.f, l2=0.f, l3=0.f;
    float4 ex0 = make_float4(0,0,0,0), ex1 = ex0;
    int ss0 = 0, ss1 = 0;
    int it = 0;
    for (int j = start + lane; j < end; j += 64, ++it) {
        int s = ssrc[j];
        float4 a = *(const float4*)&als[s * 4];
        float e0 = __expf(lrelu(a.x + aldv.x));
        float e1 = __expf(lrelu(a.y + aldv.y));
        float e2 = __expf(lrelu(a.z + aldv.z));
        float e3 = __expf(lrelu(a.w + aldv.w));
        if (it == 0)      { ex0 = make_float4(e0,e1,e2,e3); ss0 = s; }
        else if (it == 1) { ex1 = make_float4(e0,e1,e2,e3); ss1 = s; }
        l0 += e0; l1 += e1; l2 += e2; l3 += e3;
    }
    #pragma unroll
    for (int off = 32; off >= 1; off >>= 1) {
        l0 += __shfl_xor(l0, off); l1 += __shfl_xor(l1, off);
        l2 += __shfl_xor(l2, off); l3 += __shfl_xor(l3, off);
    }
    float il0 = 1.f/l0, il1 = 1.f/l1, il2 = 1.f/l2, il3 = 1.f/l3;

    const int nch = (deg + 63) >> 6;
    if (lane == 0) s_nch[wid] = nch;
    __syncthreads();
    const int maxch = max(max(s_nch[0], s_nch[1]), max(s_nch[2], s_nch[3]));

    const int h = lane >> 4;
    float s0 = 0.f, s1 = 0.f;
    for (int c = 0; c < maxch; ++c) {
        const int base = start + c * 64;
        if (c < nch) {
            int j = base + lane;
            if (j < end) {
                int s; float4 ex;
                if (c == 0)      { s = ss0; ex = ex0; }
                else if (c == 1) { s = ss1; ex = ex1; }
                else {
                    s = ssrc[j];
                    float4 a = *(const float4*)&als[s * 4];
                    ex = make_float4(__expf(lrelu(a.x + aldv.x)),
                                     __expf(lrelu(a.y + aldv.y)),
                                     __expf(lrelu(a.z + aldv.z)),
                                     __expf(lrelu(a.w + aldv.w)));
                }
                s_sidx[wid][lane] = s;
                float4 al = make_float4(ex.x*il0, ex.y*il1, ex.z*il2, ex.w*il3);
                *(float4*)&s_alpha[wid][lane * 4] = al;
            }
        }
        __syncthreads();
        if (c < nch) {
            const int cnt = min(64, end - base);
            int jj = 0;
            for (; jj + 3 < cnt; jj += 4) {
                int sA = __builtin_amdgcn_readfirstlane(s_sidx[wid][jj]);
                int sB = __builtin_amdgcn_readfirstlane(s_sidx[wid][jj + 1]);
                int sC = __builtin_amdgcn_readfirstlane(s_sidx[wid][jj + 2]);
                int sD = __builtin_amdgcn_readfirstlane(s_sidx[wid][jj + 3]);
                float aA = s_alpha[wid][jj*4 + h];
                float aB = s_alpha[wid][jj*4 + 4 + h];
                float aC = s_alpha[wid][jj*4 + 8 + h];
                float aD = s_alpha[wid][jj*4 + 12 + h];
                float2 hA = __half22float2(h1h[(size_t)sA * 64 + lane]);
                float2 hB = __half22float2(h1h[(size_t)sB * 64 + lane]);
                float2 hC = __half22float2(h1h[(size_t)sC * 64 + lane]);
                float2 hD = __half22float2(h1h[(size_t)sD * 64 + lane]);
                s0 = fmaf(hA.x, aA, s0); s1 = fmaf(hA.y, aA, s1);
                s0 = fmaf(hB.x, aB, s0); s1 = fmaf(hB.y, aB, s1);
                s0 = fmaf(hC.x, aC, s0); s1 = fmaf(hC.y, aC, s1);
                s0 = fmaf(hD.x, aD, s0); s1 = fmaf(hD.y, aD, s1);
            }
            for (; jj < cnt; ++jj) {
                int sA = __builtin_amdgcn_readfirstlane(s_sidx[wid][jj]);
                float aA = s_alpha[wid][jj*4 + h];
                float2 hA = __half22float2(h1h[(size_t)sA * 64 + lane]);
                s0 = fmaf(hA.x, aA, s0); s1 = fmaf(hA.y, aA, s1);
            }
        }
        __syncthreads();
    }
    const int col = lane << 1;
    float o0 = s0 + b1[col], o1 = s1 + b1[col + 1];
    o0 = o0 > 0.f ? o0 : expm1f(o0);         // ELU
    o1 = o1 > 0.f ? o1 : expm1f(o1);
    *(float2*)&x2[(size_t)d * 128 + col] = make_float2(o0, o1);
}

// ----------------------------------- layer-2 edge softmax+aggregate (wave/node)
__global__ __launch_bounds__(256) void edge2_kernel(const int* __restrict__ rowptr,
                                                    const int* __restrict__ ssrc,
                                                    const float* __restrict__ als,
                                                    const float* __restrict__ ald,
                                                    const float* __restrict__ h2,
                                                    const float* __restrict__ b2,
                                                    float* __restrict__ out) {
    __shared__ float s_alpha[4][64];
    __shared__ int   s_sidx[4][64];
    __shared__ int   s_nch[4];
    const int lane = threadIdx.x & 63;
    const int wid  = threadIdx.x >> 6;
    const int d = blockIdx.x * 4 + wid;
    const int start = rowptr[d], end = rowptr[d + 1];
    const int deg = end - start;
    float aldd = ald[d];

    float l = 0.f;
    float ex0 = 0.f, ex1 = 0.f;
    int ss0 = 0, ss1 = 0;
    int it = 0;
    for (int j = start + lane; j < end; j += 64, ++it) {
        int s = ssrc[j];
        float e = __expf(lrelu(als[s] + aldd));
        if (it == 0)      { ex0 = e; ss0 = s; }
        else if (it == 1) { ex1 = e; ss1 = s; }
        l += e;
    }
    #pragma unroll
    for (int off = 32; off >= 1; off >>= 1) l += __shfl_xor(l, off);
    float invl = 1.f / l;

    const int nch = (deg + 63) >> 6;
    if (lane == 0) s_nch[wid] = nch;
    __syncthreads();
    const int maxch = max(max(s_nch[0], s_nch[1]), max(s_nch[2], s_nch[3]));

    float acc = 0.f;
    for (int c = 0; c < maxch; ++c) {
        const int base = start + c * 64;
        if (c < nch) {
            int j = base + lane;
            if (j < end) {
                int s; float e;
                if (c == 0)      { s = ss0; e = ex0; }
                else if (c == 1) { s = ss1; e = ex1; }
                else { s = ssrc[j]; e = __expf(lrelu(als[s] + aldd)); }
                s_sidx[wid][lane] = s;
                s_alpha[wid][lane] = e * invl;
            }
        }
        __syncthreads();
        if (c < nch) {
            const int cnt = min(64, end - base);
            int jj = 0;
            for (; jj + 3 < cnt; jj += 4) {
                int sA = __builtin_amdgcn_readfirstlane(s_sidx[wid][jj]);
                int sB = __builtin_amdgcn_readfirstlane(s_sidx[wid][jj + 1]);
                int sC = __builtin_amdgcn_readfirstlane(s_sidx[wid][jj + 2]);
                int sD = __builtin_amdgcn_readfirstlane(s_sidx[wid][jj + 3]);
                float aA = s_alpha[wid][jj],     aB = s_alpha[wid][jj + 1];
                float aC = s_alpha[wid][jj + 2], aD = s_alpha[wid][jj + 3];
                float hA = h2[(size_t)sA * 64 + lane];
                float hB = h2[(size_t)sB * 64 + lane];
                float hC = h2[(size_t)sC * 64 + lane];
                float hD = h2[(size_t)sD * 64 + lane];
                acc = fmaf(hA, aA, acc);
                acc = fmaf(hB, aB, acc);
                acc = fmaf(hC, aC, acc);
                acc = fmaf(hD, aD, acc);
            }
            for (; jj < cnt; ++jj) {
                int sA = __builtin_amdgcn_readfirstlane(s_sidx[wid][jj]);
                float aA = s_alpha[wid][jj];
                acc = fmaf(h2[(size_t)sA * 64 + lane], aA, acc);
            }
        }
        __syncthreads();
    }
    out[(size_t)d * 64 + lane] = acc + b2[lane];
}

// ---------------------------------------------------------------------- launch
extern "C" void kernel_launch(void* const* d_in, const int* in_sizes, int n_in,
                              void* d_out, int out_size, void* d_ws, size_t ws_size,
                              hipStream_t stream) {
    const float* x   = (const float*)d_in[0];
    const void*  ei  = d_in[1];
    const float* W1  = (const float*)d_in[2];
    const float* as1 = (const float*)d_in[3];
    const float* ad1 = (const float*)d_in[4];
    const float* b1  = (const float*)d_in[5];
    const float* W2  = (const float*)d_in[6];
    const float* as2 = (const float*)d_in[7];
    const float* ad2 = (const float*)d_in[8];
    const float* b2  = (const float*)d_in[9];
    float* out = (float*)d_out;

    char* p = (char*)d_ws;
    auto alloc = [&](size_t bytes) {
        char* r = p;
        p += (bytes + 255) & ~(size_t)255;
        return r;
    };
    int2*     bpair  = (int2*)alloc(sizeof(int2) * (size_t)NBUCK * BCAP);
    int*      bcnt   = (int*)alloc(sizeof(int) * NBUCK);
    int*      bbase  = (int*)alloc(sizeof(int) * NBUCK);
    int*      ssrc   = (int*)alloc(sizeof(int) * ETOT);
    int*      rowptr = (int*)alloc(sizeof(int) * (NNODES + 1));
    int*      flag   = (int*)alloc(256);
    float*    als1   = (float*)alloc(sizeof(float) * NNODES * 4);
    float*    ald1   = (float*)alloc(sizeof(float) * NNODES * 4);
    float*    als2v  = (float*)alloc(sizeof(float) * NNODES);
    float*    ald2v  = (float*)alloc(sizeof(float) * NNODES);
    __half2*  h1h    = (__half2*)alloc(sizeof(__half2) * NNODES * 64);
    float*    x2     = (float*)alloc(sizeof(float) * NNODES * 128);
    float*    h2     = (float*)alloc(sizeof(float) * NNODES * 64);

    hipMemsetAsync(bcnt, 0, sizeof(int) * NBUCK, stream);

    detect_kernel<<<1, 128, 0, stream>>>((const unsigned int*)ei, flag);
    convert_kernel<<<CNBLK, CBT, 0, stream>>>(ei, flag, bcnt, bpair);
    bucket_scan_kernel<<<1, 1024, 0, stream>>>(bcnt, bbase, rowptr);
    bscatter_kernel<<<NBUCK, 256, 0, stream>>>(bpair, bcnt, bbase, rowptr, ssrc);
    gemm1_kernel<<<(NNODES + 63) / 64, 256, 0, stream>>>(x, W1, as1, ad1, h1h, als1, ald1);
    edge1_kernel<<<(NNODES + 3) / 4, 256, 0, stream>>>(rowptr, ssrc, als1, ald1, h1h, b1, x2);
    gemm2_kernel<<<(NNODES + 63) / 64, 256, 0, stream>>>(x2, W2, as2, ad2, h2, als2v, ald2v);
    edge2_kernel<<<(NNODES + 3) / 4, 256, 0, stream>>>(rowptr, ssrc, als2v, ald2v, h2, b2, out);
}